// Round 1
// baseline (1729.892 us; speedup 1.0000x reference)
//
#include <hip/hip_runtime.h>
#include <math.h>

#define B_ 32
#define L_ 512
#define D_ 512
#define S_ 8

__device__ __forceinline__ float sigm(float x) { return 1.0f / (1.0f + __expf(-x)); }

// ---------------------------------------------------------------------------
// Projection kernel: G1[r,s] = arg1[r,:]·Wg[:D,s]; G2[r,s] = arg2[r,:]·Wg[D:,s]
//                    S1[r,s] = arg1[r,:]·V[:D,s];  S2[r,s] = arg2[r,:]·V[D:,s]
// One wave per row r (r = b*L + i). Tiny kernel (~2.7e8 MAC total).
// ---------------------------------------------------------------------------
__global__ __launch_bounds__(256) void proj_kernel(
    const float* __restrict__ a1, const float* __restrict__ a2,
    const float* __restrict__ Wg, const float* __restrict__ V,
    float* __restrict__ G1, float* __restrict__ G2,
    float* __restrict__ S1, float* __restrict__ S2)
{
    const int wave = threadIdx.x >> 6;
    const int lane = threadIdx.x & 63;
    const int r = blockIdx.x * 4 + wave;   // 0..B*L-1
    const float* a1r = a1 + (size_t)r * D_;
    const float* a2r = a2 + (size_t)r * D_;
    float g1[S_] = {}, g2[S_] = {}, s1[S_] = {}, s2[S_] = {};
    for (int d = lane; d < D_; d += 64) {
        float x1 = a1r[d], x2 = a2r[d];
        const float* wga = Wg + d * S_;
        const float* wgb = Wg + (D_ + d) * S_;
        const float* va  = V  + d * S_;
        const float* vb  = V  + (D_ + d) * S_;
        #pragma unroll
        for (int s = 0; s < S_; ++s) {
            g1[s] += x1 * wga[s];
            g2[s] += x2 * wgb[s];
            s1[s] += x1 * va[s];
            s2[s] += x2 * vb[s];
        }
    }
    #pragma unroll
    for (int off = 32; off > 0; off >>= 1) {
        #pragma unroll
        for (int s = 0; s < S_; ++s) {
            g1[s] += __shfl_down(g1[s], off);
            g2[s] += __shfl_down(g2[s], off);
            s1[s] += __shfl_down(s1[s], off);
            s2[s] += __shfl_down(s2[s], off);
        }
    }
    if (lane == 0) {
        #pragma unroll
        for (int s = 0; s < S_; ++s) {
            G1[(size_t)r * S_ + s] = g1[s];
            G2[(size_t)r * S_ + s] = g2[s];
            S1[(size_t)r * S_ + s] = s1[s];
            S2[(size_t)r * S_ + s] = s2[s];
        }
    }
}

// ---------------------------------------------------------------------------
// GEMM A: C[r, k*512+e] = sum_d A[r,d] * Mr[k,d,e]
// A row-major [NB*L, 512]. Output C row-major [NB*L, 4096]
// (== A1 chunk layout [b_local, i, k, e]).
// 128x128 tile, BK=16, 256 threads, 8x8 microtile.
// ---------------------------------------------------------------------------
__global__ __launch_bounds__(256) void gemm_a_kernel(
    const float* __restrict__ A, const float* __restrict__ Mr,
    float* __restrict__ C)
{
    const int c0 = blockIdx.x * 128;   // 0..4095, never crosses a k boundary
    const int r0 = blockIdx.y * 128;
    const float* Bsrc = Mr + (size_t)(c0 >> 9) * (D_ * D_) + (c0 & 511);

    __shared__ __align__(16) float As[16][132];  // [kk][m], padded
    __shared__ __align__(16) float Bs[16][128];  // [kk][n]

    const int tid = threadIdx.x;
    const int tx = tid & 15, ty = tid >> 4;

    float acc[8][8];
    #pragma unroll
    for (int i = 0; i < 8; ++i)
        #pragma unroll
        for (int j = 0; j < 8; ++j) acc[i][j] = 0.f;

    for (int kt = 0; kt < D_; kt += 16) {
        // stage A (transposed into LDS)
        #pragma unroll
        for (int ch = 0; ch < 2; ++ch) {
            int c = tid + ch * 256;
            int row = c >> 2, dq = (c & 3) << 2;
            float4 v = *(const float4*)(A + (size_t)(r0 + row) * D_ + kt + dq);
            As[dq + 0][row] = v.x; As[dq + 1][row] = v.y;
            As[dq + 2][row] = v.z; As[dq + 3][row] = v.w;
        }
        // stage B (natural layout, b128 LDS writes)
        #pragma unroll
        for (int ch = 0; ch < 2; ++ch) {
            int c = tid + ch * 256;
            int dk = c >> 5, nq = (c & 31) << 2;
            *(float4*)&Bs[dk][nq] = *(const float4*)(Bsrc + (size_t)(kt + dk) * D_ + nq);
        }
        __syncthreads();
        #pragma unroll
        for (int kk = 0; kk < 16; ++kk) {
            float4 fa0 = *(const float4*)&As[kk][ty * 4];
            float4 fa1 = *(const float4*)&As[kk][ty * 4 + 64];
            float4 fb0 = *(const float4*)&Bs[kk][tx * 4];
            float4 fb1 = *(const float4*)&Bs[kk][tx * 4 + 64];
            float av[8] = {fa0.x, fa0.y, fa0.z, fa0.w, fa1.x, fa1.y, fa1.z, fa1.w};
            float bv[8] = {fb0.x, fb0.y, fb0.z, fb0.w, fb1.x, fb1.y, fb1.z, fb1.w};
            #pragma unroll
            for (int mi = 0; mi < 8; ++mi)
                #pragma unroll
                for (int ni = 0; ni < 8; ++ni)
                    acc[mi][ni] += av[mi] * bv[ni];
        }
        __syncthreads();
    }
    #pragma unroll
    for (int mi = 0; mi < 8; ++mi) {
        int row = r0 + ((mi >> 2) * 64) + ty * 4 + (mi & 3);
        float* crow = C + (size_t)row * (S_ * D_) + c0;
        *(float4*)(crow + tx * 4)      = make_float4(acc[mi][0], acc[mi][1], acc[mi][2], acc[mi][3]);
        *(float4*)(crow + 64 + tx * 4) = make_float4(acc[mi][4], acc[mi][5], acc[mi][6], acc[mi][7]);
    }
}

// ---------------------------------------------------------------------------
// GEMM B + fused epilogue:
//   bi[i,j,k] = sum_e A1[b,i,k,e] * arg2[b,j,e]
//   out[b,i,j] = sigm( sum_k U[k]*( bi*g + si*(1-g) + b[k] ) )
// M-tile = 128 rows of A1 = 16 i's x 8 k's; thread ty owns all 8 k of one i,
// so the k-reduction happens entirely in registers.
// ---------------------------------------------------------------------------
__global__ __launch_bounds__(256) void gemm_b_kernel(
    const float* __restrict__ A1,   // chunk [NB*L*S, D]
    const float* __restrict__ arg2, // full [B, L, D]
    const float* __restrict__ G1, const float* __restrict__ G2,
    const float* __restrict__ S1, const float* __restrict__ S2,
    const float* __restrict__ Bg, const float* __restrict__ U,
    const float* __restrict__ bv, float* __restrict__ out, int b0)
{
    const int bl = blockIdx.z;
    const int bg = b0 + bl;
    const int iT = blockIdx.y;          // 0..31
    const int j0 = blockIdx.x * 128;
    const float* Arows = A1 + ((size_t)bl * (L_ * S_) + iT * 128) * D_;
    const float* Brows = arg2 + (size_t)bg * L_ * D_;

    __shared__ __align__(16) float As[16][132];
    __shared__ __align__(16) float Bs[16][132];

    const int tid = threadIdx.x;
    const int tx = tid & 15, ty = tid >> 4;

    float acc[8][8];
    #pragma unroll
    for (int i = 0; i < 8; ++i)
        #pragma unroll
        for (int j = 0; j < 8; ++j) acc[i][j] = 0.f;

    for (int kt = 0; kt < D_; kt += 16) {
        #pragma unroll
        for (int ch = 0; ch < 2; ++ch) {
            int c = tid + ch * 256;
            int row = c >> 2, dq = (c & 3) << 2;
            float4 va = *(const float4*)(Arows + (size_t)row * D_ + kt + dq);
            As[dq + 0][row] = va.x; As[dq + 1][row] = va.y;
            As[dq + 2][row] = va.z; As[dq + 3][row] = va.w;
            float4 vb = *(const float4*)(Brows + (size_t)(j0 + row) * D_ + kt + dq);
            Bs[dq + 0][row] = vb.x; Bs[dq + 1][row] = vb.y;
            Bs[dq + 2][row] = vb.z; Bs[dq + 3][row] = vb.w;
        }
        __syncthreads();
        #pragma unroll
        for (int kk = 0; kk < 16; ++kk) {
            float4 fa0 = *(const float4*)&As[kk][ty * 8];
            float4 fa1 = *(const float4*)&As[kk][ty * 8 + 4];
            float4 fb0 = *(const float4*)&Bs[kk][tx * 4];
            float4 fb1 = *(const float4*)&Bs[kk][tx * 4 + 64];
            float av[8] = {fa0.x, fa0.y, fa0.z, fa0.w, fa1.x, fa1.y, fa1.z, fa1.w};
            float bvv[8] = {fb0.x, fb0.y, fb0.z, fb0.w, fb1.x, fb1.y, fb1.z, fb1.w};
            #pragma unroll
            for (int mk = 0; mk < 8; ++mk)
                #pragma unroll
                for (int nj = 0; nj < 8; ++nj)
                    acc[mk][nj] += av[mk] * bvv[nj];
        }
        __syncthreads();
    }

    // fused epilogue: thread (tx,ty) owns i = iT*16+ty, 8 j's, all 8 k
    const int i = iT * 16 + ty;
    const float* G1r = G1 + ((size_t)bg * L_ + i) * S_;
    const float* S1r = S1 + ((size_t)bg * L_ + i) * S_;
    float g1v[8], s1v[8], uv[8];
    float cbias = 0.f;
    #pragma unroll
    for (int k = 0; k < 8; ++k) {
        g1v[k] = G1r[k] + Bg[k];
        s1v[k] = S1r[k];
        uv[k]  = U[k];
        cbias += uv[k] * bv[k];
    }
    float* orow = out + ((size_t)bg * L_ + i) * L_;
    #pragma unroll
    for (int nh = 0; nh < 2; ++nh) {
        float tmp[4];
        #pragma unroll
        for (int q = 0; q < 4; ++q) {
            int nj = nh * 4 + q;
            int j = j0 + nh * 64 + tx * 4 + q;
            const float* G2r = G2 + ((size_t)bg * L_ + j) * S_;
            const float* S2r = S2 + ((size_t)bg * L_ + j) * S_;
            float pre = cbias;
            #pragma unroll
            for (int k = 0; k < 8; ++k) {
                float g  = sigm(g1v[k] + G2r[k]);
                float si = sigm(s1v[k] + S2r[k]);
                pre += uv[k] * (acc[k][nj] * g + si * (1.f - g));
            }
            tmp[q] = sigm(pre);
        }
        *(float4*)(orow + j0 + nh * 64 + tx * 4) = make_float4(tmp[0], tmp[1], tmp[2], tmp[3]);
    }
}

// ---------------------------------------------------------------------------
extern "C" void kernel_launch(void* const* d_in, const int* in_sizes, int n_in,
                              void* d_out, int out_size, void* d_ws, size_t ws_size,
                              hipStream_t stream)
{
    const float* arg1 = (const float*)d_in[0];
    const float* arg2 = (const float*)d_in[1];
    const float* Wg   = (const float*)d_in[2];
    const float* Bg   = (const float*)d_in[3];
    const float* Mr   = (const float*)d_in[4];
    const float* V    = (const float*)d_in[5];
    const float* bv   = (const float*)d_in[6];
    const float* U    = (const float*)d_in[7];
    float* out = (float*)d_out;
    float* ws  = (float*)d_ws;

    const size_t BLS = (size_t)B_ * L_ * S_;   // 131072
    float* G1 = ws;
    float* G2 = ws + BLS;
    float* S1 = ws + 2 * BLS;
    float* S2 = ws + 3 * BLS;
    float* A1 = ws + 4 * BLS;

    proj_kernel<<<dim3(B_ * L_ / 4), 256, 0, stream>>>(arg1, arg2, Wg, V, G1, G2, S1, S2);

    // pick the largest batch chunk that fits in workspace
    int NB = B_;
    while (NB > 1 && ws_size < (4 * BLS + (size_t)NB * L_ * S_ * D_) * sizeof(float)) NB >>= 1;

    for (int b0 = 0; b0 < B_; b0 += NB) {
        gemm_a_kernel<<<dim3((S_ * D_) / 128, NB * L_ / 128), 256, 0, stream>>>(
            arg1 + (size_t)b0 * L_ * D_, Mr, A1);
        gemm_b_kernel<<<dim3(L_ / 128, L_ / 16, NB), 256, 0, stream>>>(
            A1, arg2, G1, G2, S1, S2, Bg, U, bv, out, b0);
    }
}

// Round 2
// 916.704 us; speedup vs baseline: 1.8871x; 1.8871x over previous
//
#include <hip/hip_runtime.h>
#include <math.h>

#define B_ 32
#define L_ 512
#define D_ 512
#define S_ 8

using bf16x8 = __attribute__((ext_vector_type(8))) __bf16;
using bf16x4 = __attribute__((ext_vector_type(4))) __bf16;
using f32x4  = __attribute__((ext_vector_type(4))) float;

__device__ __forceinline__ float sigm(float x) { return 1.0f / (1.0f + __expf(-x)); }

__device__ __forceinline__ void stage16(const __bf16* g, __bf16* l) {
    __builtin_amdgcn_global_load_lds(
        (const __attribute__((address_space(1))) void*)g,
        (__attribute__((address_space(3))) void*)l, 16, 0, 0);
}

// ---------------------------------------------------------------------------
// Split fp32 -> bf16 hi + bf16 lo.  4 elems/thread.
// ---------------------------------------------------------------------------
__global__ __launch_bounds__(256) void conv_split_kernel(
    const float* __restrict__ x, __bf16* __restrict__ h, __bf16* __restrict__ l)
{
    const int i = blockIdx.x * 256 + threadIdx.x;
    const float4 v = ((const float4*)x)[i];
    bf16x4 hv, lv;
    const float* vp = (const float*)&v;
    #pragma unroll
    for (int c = 0; c < 4; ++c) {
        __bf16 hh = (__bf16)vp[c];
        hv[c] = hh;
        lv[c] = (__bf16)(vp[c] - (float)hh);
    }
    ((bf16x4*)h)[i] = hv;
    ((bf16x4*)l)[i] = lv;
}

// ---------------------------------------------------------------------------
// Mr [k][d][e] fp32 -> mrT hi/lo bf16 in [k][e][d] layout (transposed).
// ---------------------------------------------------------------------------
__global__ __launch_bounds__(256) void conv_mrT_kernel(
    const float* __restrict__ Mr, __bf16* __restrict__ th, __bf16* __restrict__ tl)
{
    __shared__ float tile[32][33];
    const int k = blockIdx.z;
    const int e0 = blockIdx.x * 32, d0 = blockIdx.y * 32;
    const int tx = threadIdx.x & 31, ty = threadIdx.x >> 5;   // ty 0..7
    const float* src = Mr + (size_t)k * (D_ * D_);
    #pragma unroll
    for (int i = 0; i < 4; ++i) {
        int dl = ty + i * 8;
        tile[dl][tx] = src[(size_t)(d0 + dl) * D_ + e0 + tx];
    }
    __syncthreads();
    #pragma unroll
    for (int i = 0; i < 4; ++i) {
        int el = ty + i * 8;
        float v = tile[tx][el];
        __bf16 hh = (__bf16)v;
        size_t o = (size_t)k * (D_ * D_) + (size_t)(e0 + el) * D_ + d0 + tx;
        th[o] = hh;
        tl[o] = (__bf16)(v - (float)hh);
    }
}

// ---------------------------------------------------------------------------
// Projections (fp32, tiny): G1 = arg1@Wg[:D] + Bg, G2 = arg2@Wg[D:],
// S1 = arg1@V[:D], S2 = arg2@V[D:].   One wave per row.
// ---------------------------------------------------------------------------
__global__ __launch_bounds__(256) void proj_kernel(
    const float* __restrict__ a1, const float* __restrict__ a2,
    const float* __restrict__ Wg, const float* __restrict__ V,
    const float* __restrict__ Bg,
    float* __restrict__ G1, float* __restrict__ G2,
    float* __restrict__ S1, float* __restrict__ S2)
{
    const int wave = threadIdx.x >> 6;
    const int lane = threadIdx.x & 63;
    const int r = blockIdx.x * 4 + wave;
    const float* a1r = a1 + (size_t)r * D_;
    const float* a2r = a2 + (size_t)r * D_;
    float g1[S_] = {}, g2[S_] = {}, s1[S_] = {}, s2[S_] = {};
    for (int d = lane; d < D_; d += 64) {
        float x1 = a1r[d], x2 = a2r[d];
        const float* wga = Wg + d * S_;
        const float* wgb = Wg + (D_ + d) * S_;
        const float* va  = V  + d * S_;
        const float* vb  = V  + (D_ + d) * S_;
        #pragma unroll
        for (int s = 0; s < S_; ++s) {
            g1[s] += x1 * wga[s];
            g2[s] += x2 * wgb[s];
            s1[s] += x1 * va[s];
            s2[s] += x2 * vb[s];
        }
    }
    #pragma unroll
    for (int off = 32; off > 0; off >>= 1) {
        #pragma unroll
        for (int s = 0; s < S_; ++s) {
            g1[s] += __shfl_down(g1[s], off);
            g2[s] += __shfl_down(g2[s], off);
            s1[s] += __shfl_down(s1[s], off);
            s2[s] += __shfl_down(s2[s], off);
        }
    }
    if (lane == 0) {
        #pragma unroll
        for (int s = 0; s < S_; ++s) {
            G1[(size_t)r * S_ + s] = g1[s] + Bg[s];
            G2[(size_t)r * S_ + s] = g2[s];
            S1[(size_t)r * S_ + s] = s1[s];
            S2[(size_t)r * S_ + s] = s2[s];
        }
    }
}

// ---------------------------------------------------------------------------
// GEMM A (split-bf16 MFMA): C[r][n] = sum_d arg1[r,d] * Mr[k,d,e], n=k*512+e.
// A rows = a1 hi/lo [r][d]; B^T rows = mrT hi/lo [n][d].
// Output written as bf16 hi/lo via LDS-transpose epilogue.
// 128x128 tile, BK=32, 4 waves (2x2), 4x4 mfma tiles/wave, 3-product split.
// ---------------------------------------------------------------------------
__global__ __launch_bounds__(256) void gemm_a_kernel(
    const __bf16* __restrict__ Ah, const __bf16* __restrict__ Al,
    const __bf16* __restrict__ Bh, const __bf16* __restrict__ Bl,
    __bf16* __restrict__ Ch, __bf16* __restrict__ Cl)
{
    __shared__ __align__(16) __bf16 lds[16384];   // 32 KB
    __bf16* As_h = lds;
    __bf16* As_l = lds + 4096;
    __bf16* Bs_h = lds + 8192;
    __bf16* Bs_l = lds + 12288;

    const int t = threadIdx.x;
    const int lane = t & 63, wv = t >> 6;
    const int wm = wv >> 1, wn = wv & 1;
    const int q = lane >> 4, i15 = lane & 15;
    const int r0 = blockIdx.y * 128;
    const int c0 = blockIdx.x * 128;

    f32x4 acc[4][4];
    const f32x4 zero = {0.f, 0.f, 0.f, 0.f};
    #pragma unroll
    for (int a = 0; a < 4; ++a)
        #pragma unroll
        for (int b = 0; b < 4; ++b) acc[a][b] = zero;

    for (int kt = 0; kt < D_; kt += 32) {
        #pragma unroll
        for (int c = 0; c < 2; ++c) {
            const int s = t + c * 256;
            const int kq = s >> 7, m = s & 127;
            const size_t ga = (size_t)(r0 + m) * D_ + kt + kq * 8;
            const size_t gb = (size_t)(c0 + m) * D_ + kt + kq * 8;
            stage16(Ah + ga, As_h + s * 8);
            stage16(Al + ga, As_l + s * 8);
            stage16(Bh + gb, Bs_h + s * 8);
            stage16(Bl + gb, Bs_l + s * 8);
        }
        __syncthreads();
        bf16x8 bh[4], bl[4];
        #pragma unroll
        for (int nt = 0; nt < 4; ++nt) {
            const int n = wn * 64 + nt * 16 + i15;
            bh[nt] = *(const bf16x8*)(Bs_h + (q * 128 + n) * 8);
            bl[nt] = *(const bf16x8*)(Bs_l + (q * 128 + n) * 8);
        }
        #pragma unroll
        for (int mt = 0; mt < 4; ++mt) {
            const int m = wm * 64 + mt * 16 + i15;
            bf16x8 ah = *(const bf16x8*)(As_h + (q * 128 + m) * 8);
            bf16x8 al = *(const bf16x8*)(As_l + (q * 128 + m) * 8);
            #pragma unroll
            for (int nt = 0; nt < 4; ++nt) {
                acc[mt][nt] = __builtin_amdgcn_mfma_f32_16x16x32_bf16(ah, bh[nt], acc[mt][nt], 0, 0, 0);
                acc[mt][nt] = __builtin_amdgcn_mfma_f32_16x16x32_bf16(ah, bl[nt], acc[mt][nt], 0, 0, 0);
                acc[mt][nt] = __builtin_amdgcn_mfma_f32_16x16x32_bf16(al, bh[nt], acc[mt][nt], 0, 0, 0);
            }
        }
        __syncthreads();
    }

    // epilogue: per-wave LDS transpose -> coalesced hi/lo bf16 stores
    float* scr = (float*)lds + wv * 1344;   // 16 rows x 84 (pad: 2-way banks)
    #pragma unroll
    for (int mt = 0; mt < 4; ++mt) {
        #pragma unroll
        for (int nt = 0; nt < 4; ++nt)
            #pragma unroll
            for (int r = 0; r < 4; ++r)
                scr[(q * 4 + r) * 84 + nt * 16 + i15] = acc[mt][nt][r];
        __builtin_amdgcn_s_waitcnt(0);
        const int rr0 = r0 + wm * 64 + mt * 16;
        const size_t cb = (size_t)c0 + wn * 64 + lane;
        #pragma unroll
        for (int r = 0; r < 16; ++r) {
            float v = scr[r * 84 + lane];
            __bf16 h = (__bf16)v;
            __bf16 lo = (__bf16)(v - (float)h);
            const size_t o = (size_t)(rr0 + r) * (S_ * D_) + cb;
            Ch[o] = h;
            Cl[o] = lo;
        }
        __builtin_amdgcn_s_waitcnt(0);
    }
}

// ---------------------------------------------------------------------------
// GEMM B (split-bf16 MFMA) + fused epilogue.
// A rows = A1 hi/lo [(bl,i,k)][e]; B^T rows = a2 hi/lo [(bl,j)][e].
// C row m = i*8+k. Epilogue: g/si sigmoids, U-weighted k-reduction via
// shfl_xor(16), final sigmoid, store out[b,i,j].
// ---------------------------------------------------------------------------
__global__ __launch_bounds__(256) void gemm_b_kernel(
    const __bf16* __restrict__ A1h, const __bf16* __restrict__ A1l,
    const __bf16* __restrict__ a2h, const __bf16* __restrict__ a2l,
    const float* __restrict__ G1, const float* __restrict__ G2,
    const float* __restrict__ S1, const float* __restrict__ S2,
    const float* __restrict__ U, const float* __restrict__ bvec,
    float* __restrict__ out, int b0)
{
    __shared__ __align__(16) __bf16 lds[16384];
    __bf16* As_h = lds;
    __bf16* As_l = lds + 4096;
    __bf16* Bs_h = lds + 8192;
    __bf16* Bs_l = lds + 12288;

    const int t = threadIdx.x;
    const int lane = t & 63, wv = t >> 6;
    const int wm = wv >> 1, wn = wv & 1;
    const int q = lane >> 4, i15 = lane & 15;
    const int bl = blockIdx.z;
    const int bg = b0 + bl;
    const int m0g = blockIdx.y * 128;
    const int j0 = blockIdx.x * 128;

    f32x4 acc[4][4];
    const f32x4 zero = {0.f, 0.f, 0.f, 0.f};
    #pragma unroll
    for (int a = 0; a < 4; ++a)
        #pragma unroll
        for (int b = 0; b < 4; ++b) acc[a][b] = zero;

    for (int kt = 0; kt < D_; kt += 32) {
        #pragma unroll
        for (int c = 0; c < 2; ++c) {
            const int s = t + c * 256;
            const int kq = s >> 7, m = s & 127;
            const size_t ga = ((size_t)bl * (L_ * S_) + m0g + m) * D_ + kt + kq * 8;
            const size_t gb = ((size_t)bl * L_ + j0 + m) * D_ + kt + kq * 8;
            stage16(A1h + ga, As_h + s * 8);
            stage16(A1l + ga, As_l + s * 8);
            stage16(a2h + gb, Bs_h + s * 8);
            stage16(a2l + gb, Bs_l + s * 8);
        }
        __syncthreads();
        bf16x8 bh[4], bl_[4];
        #pragma unroll
        for (int nt = 0; nt < 4; ++nt) {
            const int n = wn * 64 + nt * 16 + i15;
            bh[nt]  = *(const bf16x8*)(Bs_h + (q * 128 + n) * 8);
            bl_[nt] = *(const bf16x8*)(Bs_l + (q * 128 + n) * 8);
        }
        #pragma unroll
        for (int mt = 0; mt < 4; ++mt) {
            const int m = wm * 64 + mt * 16 + i15;
            bf16x8 ah = *(const bf16x8*)(As_h + (q * 128 + m) * 8);
            bf16x8 al = *(const bf16x8*)(As_l + (q * 128 + m) * 8);
            #pragma unroll
            for (int nt = 0; nt < 4; ++nt) {
                acc[mt][nt] = __builtin_amdgcn_mfma_f32_16x16x32_bf16(ah, bh[nt],  acc[mt][nt], 0, 0, 0);
                acc[mt][nt] = __builtin_amdgcn_mfma_f32_16x16x32_bf16(ah, bl_[nt], acc[mt][nt], 0, 0, 0);
                acc[mt][nt] = __builtin_amdgcn_mfma_f32_16x16x32_bf16(al, bh[nt],  acc[mt][nt], 0, 0, 0);
            }
        }
        __syncthreads();
    }

    // fused epilogue
    float cbias = 0.f;
    #pragma unroll
    for (int k = 0; k < 8; ++k) cbias += U[k] * bvec[k];
    const int kh = q & 1;
    const float4 Us = *(const float4*)(U + kh * 4);
    const float* Usp = (const float*)&Us;
    const int ib0 = (m0g + wm * 64) >> 3;

    #pragma unroll
    for (int mt = 0; mt < 4; ++mt) {
        const int iA = ib0 + mt * 2 + (q >> 1);
        const float4 g1 = *(const float4*)(G1 + ((size_t)bg * L_ + iA) * S_ + kh * 4);
        const float4 s1 = *(const float4*)(S1 + ((size_t)bg * L_ + iA) * S_ + kh * 4);
        const float* g1p = (const float*)&g1;
        const float* s1p = (const float*)&s1;
        #pragma unroll
        for (int nt = 0; nt < 4; ++nt) {
            const int j = j0 + wn * 64 + nt * 16 + i15;
            const float4 g2 = *(const float4*)(G2 + ((size_t)bg * L_ + j) * S_ + kh * 4);
            const float4 s2 = *(const float4*)(S2 + ((size_t)bg * L_ + j) * S_ + kh * 4);
            const float* g2p = (const float*)&g2;
            const float* s2p = (const float*)&s2;
            float p = 0.f;
            #pragma unroll
            for (int r = 0; r < 4; ++r) {
                const float g  = sigm(g1p[r] + g2p[r]);
                const float si = sigm(s1p[r] + s2p[r]);
                p += Usp[r] * (acc[mt][nt][r] * g + si * (1.f - g));
            }
            p += __shfl_xor(p, 16);
            const float val = sigm(p + cbias);
            if (kh == 0) out[((size_t)bg * L_ + iA) * L_ + j] = val;
        }
    }
}

// ---------------------------------------------------------------------------
extern "C" void kernel_launch(void* const* d_in, const int* in_sizes, int n_in,
                              void* d_out, int out_size, void* d_ws, size_t ws_size,
                              hipStream_t stream)
{
    const float* arg1 = (const float*)d_in[0];
    const float* arg2 = (const float*)d_in[1];
    const float* Wg   = (const float*)d_in[2];
    const float* Bg   = (const float*)d_in[3];
    const float* Mr   = (const float*)d_in[4];
    const float* V    = (const float*)d_in[5];
    const float* bvec = (const float*)d_in[6];
    const float* U    = (const float*)d_in[7];
    float* out = (float*)d_out;

    char* w = (char*)d_ws;
    size_t off = 0;
    auto nxt = [&](size_t bytes) -> void* {
        void* p = w + off;
        off = (off + bytes + 255) & ~(size_t)255;
        return p;
    };

    __bf16* mrTh = (__bf16*)nxt((size_t)S_ * D_ * D_ * 2);
    __bf16* mrTl = (__bf16*)nxt((size_t)S_ * D_ * D_ * 2);
    float* G1 = (float*)nxt((size_t)B_ * L_ * S_ * 4);
    float* G2 = (float*)nxt((size_t)B_ * L_ * S_ * 4);
    float* S1 = (float*)nxt((size_t)B_ * L_ * S_ * 4);
    float* S2 = (float*)nxt((size_t)B_ * L_ * S_ * 4);
    const size_t fixed = off;

    // per-batch chunk bytes: a1h/l + a2h/l (4 x 512KB) + A1h/l (2 x 4MB)
    const size_t perb = 4 * ((size_t)L_ * D_ * 2) + 2 * ((size_t)L_ * S_ * D_ * 2);
    int NB = 32;
    while (NB > 1 && fixed + (size_t)NB * perb + 8 * 256 > ws_size) NB >>= 1;

    __bf16* a1h = (__bf16*)nxt((size_t)NB * L_ * D_ * 2);
    __bf16* a1l = (__bf16*)nxt((size_t)NB * L_ * D_ * 2);
    __bf16* a2h = (__bf16*)nxt((size_t)NB * L_ * D_ * 2);
    __bf16* a2l = (__bf16*)nxt((size_t)NB * L_ * D_ * 2);
    __bf16* A1h = (__bf16*)nxt((size_t)NB * L_ * S_ * D_ * 2);
    __bf16* A1l = (__bf16*)nxt((size_t)NB * L_ * S_ * D_ * 2);

    conv_mrT_kernel<<<dim3(16, 16, 8), 256, 0, stream>>>(Mr, mrTh, mrTl);
    proj_kernel<<<dim3(B_ * L_ / 4), 256, 0, stream>>>(arg1, arg2, Wg, V, Bg, G1, G2, S1, S2);

    for (int b0 = 0; b0 < B_; b0 += NB) {
        const int nblk = NB * L_ * D_ / 4 / 256;
        conv_split_kernel<<<dim3(nblk), 256, 0, stream>>>(arg1 + (size_t)b0 * L_ * D_, a1h, a1l);
        conv_split_kernel<<<dim3(nblk), 256, 0, stream>>>(arg2 + (size_t)b0 * L_ * D_, a2h, a2l);
        gemm_a_kernel<<<dim3((S_ * D_) / 128, NB * L_ / 128), 256, 0, stream>>>(
            a1h, a1l, mrTh, mrTl, A1h, A1l);
        gemm_b_kernel<<<dim3(L_ / 128, (L_ * S_) / 128, NB), 256, 0, stream>>>(
            A1h, A1l, a2h, a2l, G1, G2, S1, S2, U, bvec, out, b0);
    }
}

// Round 3
// 558.512 us; speedup vs baseline: 3.0973x; 1.6413x over previous
//
#include <hip/hip_runtime.h>
#include <math.h>

#define B_ 32
#define L_ 512
#define D_ 512
#define S_ 8

using f16x8 = __attribute__((ext_vector_type(8))) _Float16;
using f32x4 = __attribute__((ext_vector_type(4))) float;

__device__ __forceinline__ float sigm(float x) { return 1.0f / (1.0f + __expf(-x)); }

__device__ __forceinline__ void stage16(const _Float16* g, _Float16* l) {
    __builtin_amdgcn_global_load_lds(
        (const __attribute__((address_space(1))) void*)g,
        (__attribute__((address_space(3))) void*)l, 16, 0, 0);
}

// ---------------------------------------------------------------------------
// fp32 rows -> tiled fp16 [rtile][kt16][kq4][row128][8]  (hi, optional lo)
// ---------------------------------------------------------------------------
__global__ __launch_bounds__(256) void conv_tiled_kernel(
    const float* __restrict__ in, _Float16* __restrict__ outh,
    _Float16* __restrict__ outl)
{
    __shared__ __align__(16) float scr[4096];     // [kq4][row128][8]
    const int t = threadIdx.x;
    const size_t base_in  = (size_t)blockIdx.x * 128 * D_;
    const size_t base_out = (size_t)blockIdx.x * 65536;
    for (int kt = 0; kt < 16; ++kt) {
        if (kt) __syncthreads();
        #pragma unroll
        for (int f = 0; f < 4; ++f) {
            const int fi = t + f * 256;            // 0..1023
            const int row = fi >> 3, c4 = fi & 7;
            float4 v = *(const float4*)(in + base_in + (size_t)row * D_ + kt * 32 + c4 * 4);
            *(float4*)(scr + ((c4 >> 1) * 128 + row) * 8 + (c4 & 1) * 4) = v;
        }
        __syncthreads();
        #pragma unroll
        for (int c = 0; c < 2; ++c) {
            const int s = t + c * 256;             // 0..511
            const float4 v0 = *(const float4*)(scr + s * 8);
            const float4 v1 = *(const float4*)(scr + s * 8 + 4);
            const float vv[8] = {v0.x, v0.y, v0.z, v0.w, v1.x, v1.y, v1.z, v1.w};
            f16x8 h, l;
            #pragma unroll
            for (int i = 0; i < 8; ++i) {
                _Float16 hh = (_Float16)vv[i];
                h[i] = hh;
                l[i] = (_Float16)(vv[i] - (float)hh);
            }
            *(f16x8*)(outh + base_out + kt * 4096 + s * 8) = h;
            if (outl) *(f16x8*)(outl + base_out + kt * 4096 + s * 8) = l;
        }
    }
}

// ---------------------------------------------------------------------------
// Mr [k][d][e] fp32 -> single fp16 tiled over n=k*512+e: [ntile][kt_d][kq][n128][8d]
// ---------------------------------------------------------------------------
__global__ __launch_bounds__(256) void conv_mrT_kernel(
    const float* __restrict__ Mr, _Float16* __restrict__ out)
{
    __shared__ float tile[32][33];
    const int k = blockIdx.z;
    const int e0 = blockIdx.x * 32, d0 = blockIdx.y * 32;
    const int tx = threadIdx.x & 31, ty = threadIdx.x >> 5;
    #pragma unroll
    for (int i = 0; i < 4; ++i) {
        const int dl = ty + i * 8;
        tile[dl][tx] = Mr[(size_t)k * (D_ * D_) + (size_t)(d0 + dl) * D_ + e0 + tx];
    }
    __syncthreads();
    if (threadIdx.x < 128) {
        const int el = threadIdx.x & 31, dc = threadIdx.x >> 5;   // dc 0..3
        f16x8 h;
        #pragma unroll
        for (int i = 0; i < 8; ++i) h[i] = (_Float16)tile[dc * 8 + i][el];
        const int e = e0 + el, d = d0 + dc * 8;
        const size_t addr = (size_t)(k * 4 + (e >> 7)) * 65536
                          + (size_t)(d >> 5) * 4096 + ((d >> 3) & 3) * 1024
                          + (size_t)(e & 127) * 8;
        *(f16x8*)(out + addr) = h;
    }
}

// ---------------------------------------------------------------------------
// Projections (fp32, tiny)
// ---------------------------------------------------------------------------
__global__ __launch_bounds__(256) void proj_kernel(
    const float* __restrict__ a1, const float* __restrict__ a2,
    const float* __restrict__ Wg, const float* __restrict__ V,
    const float* __restrict__ Bg,
    float* __restrict__ G1, float* __restrict__ G2,
    float* __restrict__ S1, float* __restrict__ S2)
{
    const int wave = threadIdx.x >> 6;
    const int lane = threadIdx.x & 63;
    const int r = blockIdx.x * 4 + wave;
    const float* a1r = a1 + (size_t)r * D_;
    const float* a2r = a2 + (size_t)r * D_;
    float g1[S_] = {}, g2[S_] = {}, s1[S_] = {}, s2[S_] = {};
    for (int d = lane; d < D_; d += 64) {
        float x1 = a1r[d], x2 = a2r[d];
        const float* wga = Wg + d * S_;
        const float* wgb = Wg + (D_ + d) * S_;
        const float* va  = V  + d * S_;
        const float* vb  = V  + (D_ + d) * S_;
        #pragma unroll
        for (int s = 0; s < S_; ++s) {
            g1[s] += x1 * wga[s];
            g2[s] += x2 * wgb[s];
            s1[s] += x1 * va[s];
            s2[s] += x2 * vb[s];
        }
    }
    #pragma unroll
    for (int off = 32; off > 0; off >>= 1) {
        #pragma unroll
        for (int s = 0; s < S_; ++s) {
            g1[s] += __shfl_down(g1[s], off);
            g2[s] += __shfl_down(g2[s], off);
            s1[s] += __shfl_down(s1[s], off);
            s2[s] += __shfl_down(s2[s], off);
        }
    }
    if (lane == 0) {
        #pragma unroll
        for (int s = 0; s < S_; ++s) {
            G1[(size_t)r * S_ + s] = g1[s] + Bg[s];
            G2[(size_t)r * S_ + s] = g2[s];
            S1[(size_t)r * S_ + s] = s1[s];
            S2[(size_t)r * S_ + s] = s2[s];
        }
    }
}

// ---------------------------------------------------------------------------
// GEMM A: A1 = a1 @ Mr  (2-product fp16 split on a1; Mr single fp16).
// A operand: a1 tiled hi/lo; B operand: mrT tiled. BK=64.
// Output: A1 single fp16, tiled [itile][kt_e][kq_e][m=k*16+i15][8e].
// ---------------------------------------------------------------------------
__global__ __launch_bounds__(256) void gemm_a_kernel(
    const _Float16* __restrict__ Ah, const _Float16* __restrict__ Al,
    const _Float16* __restrict__ Bt, _Float16* __restrict__ C)
{
    __shared__ __align__(16) _Float16 lds[24576];   // 48 KB: Ash/Asl/Bs
    _Float16* Ash = lds;
    _Float16* Asl = lds + 8192;
    _Float16* Bsh = lds + 16384;

    const int t = threadIdx.x;
    const int lane = t & 63, wv = t >> 6;
    const int wm = wv >> 1, wn = wv & 1;
    const int q = lane >> 4, i15 = lane & 15;
    const int ntile = blockIdx.x;                  // 0..31
    const int r0 = blockIdx.y * 128;               // chunk-local row
    const size_t abase = (size_t)blockIdx.y * 65536;
    const size_t bbase = (size_t)ntile * 65536;
    const int kblk = ntile >> 2;
    const int e0 = (ntile & 3) * 128;

    f32x4 acc[4][4];
    const f32x4 zero = {0.f, 0.f, 0.f, 0.f};
    #pragma unroll
    for (int a = 0; a < 4; ++a)
        #pragma unroll
        for (int b = 0; b < 4; ++b) acc[a][b] = zero;

    for (int kt2 = 0; kt2 < 8; ++kt2) {
        const size_t ab = abase + kt2 * 8192;
        const size_t bb = bbase + kt2 * 8192;
        #pragma unroll
        for (int c = 0; c < 4; ++c) {
            const int s8 = t + c * 256;
            stage16(Ah + ab + s8 * 8, Ash + s8 * 8);
            stage16(Al + ab + s8 * 8, Asl + s8 * 8);
            stage16(Bt + bb + s8 * 8, Bsh + s8 * 8);
        }
        __syncthreads();
        #pragma unroll
        for (int kk2 = 0; kk2 < 2; ++kk2) {
            const int kq = kk2 * 4 + q;
            f16x8 bfr[4];
            #pragma unroll
            for (int nt = 0; nt < 4; ++nt)
                bfr[nt] = *(const f16x8*)(Bsh + ((size_t)kq * 128 + wn * 64 + nt * 16 + i15) * 8);
            #pragma unroll
            for (int mt = 0; mt < 4; ++mt) {
                const int m = wm * 64 + mt * 16 + i15;
                f16x8 ah = *(const f16x8*)(Ash + ((size_t)kq * 128 + m) * 8);
                f16x8 al = *(const f16x8*)(Asl + ((size_t)kq * 128 + m) * 8);
                #pragma unroll
                for (int nt = 0; nt < 4; ++nt) {
                    acc[mt][nt] = __builtin_amdgcn_mfma_f32_16x16x32_f16(ah, bfr[nt], acc[mt][nt], 0, 0, 0);
                    acc[mt][nt] = __builtin_amdgcn_mfma_f32_16x16x32_f16(al, bfr[nt], acc[mt][nt], 0, 0, 0);
                }
            }
        }
        __syncthreads();
    }

    // epilogue: per-wave LDS transpose -> tiled fp16 A1, 256B-contiguous stores
    float* scr = (float*)lds + wv * 1104;           // 16 x 68 floats
    #pragma unroll
    for (int mt = 0; mt < 4; ++mt) {
        #pragma unroll
        for (int nt = 0; nt < 4; ++nt)
            #pragma unroll
            for (int r = 0; r < 4; ++r)
                scr[(q * 4 + r) * 68 + nt * 16 + i15] = acc[mt][nt][r];
        __builtin_amdgcn_s_waitcnt(0);
        #pragma unroll
        for (int cc = 0; cc < 2; ++cc) {
            const int row = lane & 15;
            const int ech = (lane >> 4) + cc * 4;   // 0..7
            const float4 v0 = *(const float4*)(scr + row * 68 + ech * 8);
            const float4 v1 = *(const float4*)(scr + row * 68 + ech * 8 + 4);
            const float vv[8] = {v0.x, v0.y, v0.z, v0.w, v1.x, v1.y, v1.z, v1.w};
            f16x8 h;
            #pragma unroll
            for (int i = 0; i < 8; ++i) h[i] = (_Float16)vv[i];
            const int e = e0 + wn * 64 + ech * 8;
            const int ig = r0 + wm * 64 + mt * 16 + row;
            const size_t addr = (size_t)(ig >> 4) * 65536
                              + (size_t)(e >> 5) * 4096 + ((e >> 3) & 3) * 1024
                              + (size_t)(kblk * 16 + row) * 8;
            *(f16x8*)(C + addr) = h;
        }
        __builtin_amdgcn_s_waitcnt(0);
    }
}

// ---------------------------------------------------------------------------
// GEMM B (single-product fp16) + fused epilogue.
// A: A1 tiled [tile=bl*32+y][kt][kq][m=k*16+i15][8]; B: a2 tiled [bl*4+jt][...].
// k = wm*4+mt per thread; in-register mt-reduction + cross-wave LDS exchange.
// ---------------------------------------------------------------------------
__global__ __launch_bounds__(256) void gemm_b_kernel(
    const _Float16* __restrict__ A1, const _Float16* __restrict__ a2t,
    const float* __restrict__ G1, const float* __restrict__ G2,
    const float* __restrict__ S1, const float* __restrict__ S2,
    const float* __restrict__ U, const float* __restrict__ bvec,
    float* __restrict__ out, int b0)
{
    __shared__ __align__(16) _Float16 lds[16384];   // 32 KB: As/Bs
    _Float16* As = lds;
    _Float16* Bs = lds + 8192;

    const int t = threadIdx.x;
    const int lane = t & 63, wv = t >> 6;
    const int wm = wv >> 1, wn = wv & 1;
    const int q = lane >> 4, i15 = lane & 15;
    const int bl = blockIdx.z;
    const int bg = b0 + bl;
    const int y = blockIdx.y;                       // 0..31 (i16-group)
    const int jt = blockIdx.x;                      // 0..3
    const int j0 = jt * 128;
    const size_t abase = (size_t)(bl * 32 + y) * 65536;
    const size_t bbase = (size_t)(bl * 4 + jt) * 65536;

    f32x4 acc[4][4];
    const f32x4 zero = {0.f, 0.f, 0.f, 0.f};
    #pragma unroll
    for (int a = 0; a < 4; ++a)
        #pragma unroll
        for (int b = 0; b < 4; ++b) acc[a][b] = zero;

    for (int kt2 = 0; kt2 < 8; ++kt2) {
        const size_t ab = abase + kt2 * 8192;
        const size_t bb = bbase + kt2 * 8192;
        #pragma unroll
        for (int c = 0; c < 4; ++c) {
            const int s8 = t + c * 256;
            stage16(A1 + ab + s8 * 8, As + s8 * 8);
            stage16(a2t + bb + s8 * 8, Bs + s8 * 8);
        }
        __syncthreads();
        #pragma unroll
        for (int kk2 = 0; kk2 < 2; ++kk2) {
            const int kq = kk2 * 4 + q;
            f16x8 bfr[4];
            #pragma unroll
            for (int nt = 0; nt < 4; ++nt)
                bfr[nt] = *(const f16x8*)(Bs + ((size_t)kq * 128 + wn * 64 + nt * 16 + i15) * 8);
            #pragma unroll
            for (int mt = 0; mt < 4; ++mt) {
                const int m = wm * 64 + mt * 16 + i15;
                f16x8 a = *(const f16x8*)(As + ((size_t)kq * 128 + m) * 8);
                #pragma unroll
                for (int nt = 0; nt < 4; ++nt)
                    acc[mt][nt] = __builtin_amdgcn_mfma_f32_16x16x32_f16(a, bfr[nt], acc[mt][nt], 0, 0, 0);
            }
        }
        __syncthreads();
    }

    // epilogue: thread covers i = y*16 + q*4 + r (4 i), j (4 nt), k = wm*4+mt (4 k)
    float U4[4];
    float cbias = 0.f;
    #pragma unroll
    for (int k = 0; k < 8; ++k) cbias += U[k] * bvec[k];
    #pragma unroll
    for (int mt = 0; mt < 4; ++mt) U4[mt] = U[wm * 4 + mt];

    float g1v[4][4], s1v[4][4];
    #pragma unroll
    for (int r = 0; r < 4; ++r) {
        const int ig = y * 16 + q * 4 + r;
        const float4 g1 = *(const float4*)(G1 + ((size_t)bg * L_ + ig) * S_ + wm * 4);
        const float4 s1 = *(const float4*)(S1 + ((size_t)bg * L_ + ig) * S_ + wm * 4);
        g1v[r][0] = g1.x; g1v[r][1] = g1.y; g1v[r][2] = g1.z; g1v[r][3] = g1.w;
        s1v[r][0] = s1.x; s1v[r][1] = s1.y; s1v[r][2] = s1.z; s1v[r][3] = s1.w;
    }

    float part[4][4];   // [nt][r]
    #pragma unroll
    for (int nt = 0; nt < 4; ++nt) {
        const int j = j0 + wn * 64 + nt * 16 + i15;
        const float4 g2 = *(const float4*)(G2 + ((size_t)bg * L_ + j) * S_ + wm * 4);
        const float4 s2 = *(const float4*)(S2 + ((size_t)bg * L_ + j) * S_ + wm * 4);
        const float g2p[4] = {g2.x, g2.y, g2.z, g2.w};
        const float s2p[4] = {s2.x, s2.y, s2.z, s2.w};
        #pragma unroll
        for (int r = 0; r < 4; ++r) {
            float p = 0.f;
            #pragma unroll
            for (int mt = 0; mt < 4; ++mt) {
                const float g  = sigm(g1v[r][mt] + g2p[mt]);
                const float si = sigm(s1v[r][mt] + s2p[mt]);
                p += U4[mt] * (acc[mt][nt][r] * g + si * (1.f - g));
            }
            part[nt][r] = p;
        }
    }

    // cross-wave k-half exchange (wm=0 <-> wm=1 partner = t +/- 128)
    float* xb = (float*)lds;                        // 16 KB
    #pragma unroll
    for (int nt = 0; nt < 4; ++nt)
        *(float4*)(xb + t * 16 + nt * 4) = *(const float4*)&part[nt][0];
    __syncthreads();
    if (wm == 0) {
        #pragma unroll
        for (int nt = 0; nt < 4; ++nt) {
            const int j = j0 + wn * 64 + nt * 16 + i15;
            const float4 o = *(const float4*)(xb + (t + 128) * 16 + nt * 4);
            const float op[4] = {o.x, o.y, o.z, o.w};
            #pragma unroll
            for (int r = 0; r < 4; ++r) {
                const int ig = y * 16 + q * 4 + r;
                out[((size_t)bg * L_ + ig) * L_ + j] = sigm(part[nt][r] + op[r] + cbias);
            }
        }
    }
}

// ---------------------------------------------------------------------------
extern "C" void kernel_launch(void* const* d_in, const int* in_sizes, int n_in,
                              void* d_out, int out_size, void* d_ws, size_t ws_size,
                              hipStream_t stream)
{
    const float* arg1 = (const float*)d_in[0];
    const float* arg2 = (const float*)d_in[1];
    const float* Wg   = (const float*)d_in[2];
    const float* Bg   = (const float*)d_in[3];
    const float* Mr   = (const float*)d_in[4];
    const float* V    = (const float*)d_in[5];
    const float* bvec = (const float*)d_in[6];
    const float* U    = (const float*)d_in[7];
    float* out = (float*)d_out;

    char* w = (char*)d_ws;
    size_t off = 0;
    auto nxt = [&](size_t bytes) -> void* {
        void* p = w + off;
        off = (off + bytes + 255) & ~(size_t)255;
        return p;
    };

    _Float16* mrT = (_Float16*)nxt((size_t)S_ * D_ * D_ * 2);
    float* G1 = (float*)nxt((size_t)B_ * L_ * S_ * 4);
    float* G2 = (float*)nxt((size_t)B_ * L_ * S_ * 4);
    float* S1 = (float*)nxt((size_t)B_ * L_ * S_ * 4);
    float* S2 = (float*)nxt((size_t)B_ * L_ * S_ * 4);
    const size_t fixed = off;

    // per-batch: a1h + a1l + a2h (3 x 512KB) + A1 (4MB)
    const size_t perb = 3 * ((size_t)L_ * D_ * 2) + (size_t)L_ * S_ * D_ * 2;
    int NB = 32;
    while (NB > 1 && fixed + (size_t)NB * perb + 4096 > ws_size) NB >>= 1;

    _Float16* a1h = (_Float16*)nxt((size_t)NB * L_ * D_ * 2);
    _Float16* a1l = (_Float16*)nxt((size_t)NB * L_ * D_ * 2);
    _Float16* a2h = (_Float16*)nxt((size_t)NB * L_ * D_ * 2);
    _Float16* A1  = (_Float16*)nxt((size_t)NB * L_ * S_ * D_ * 2);

    conv_mrT_kernel<<<dim3(16, 16, 8), 256, 0, stream>>>(Mr, mrT);
    proj_kernel<<<dim3(B_ * L_ / 4), 256, 0, stream>>>(arg1, arg2, Wg, V, Bg, G1, G2, S1, S2);

    for (int b0 = 0; b0 < B_; b0 += NB) {
        conv_tiled_kernel<<<dim3(NB * 4), 256, 0, stream>>>(arg1 + (size_t)b0 * L_ * D_, a1h, a1l);
        conv_tiled_kernel<<<dim3(NB * 4), 256, 0, stream>>>(arg2 + (size_t)b0 * L_ * D_, a2h, nullptr);
        gemm_a_kernel<<<dim3(32, NB * 4), 256, 0, stream>>>(a1h, a1l, mrT, A1);
        gemm_b_kernel<<<dim3(4, 32, NB), 256, 0, stream>>>(
            A1, a2h, G1, G2, S1, S2, U, bvec, out, b0);
    }
}

// Round 4
// 497.560 us; speedup vs baseline: 3.4767x; 1.1225x over previous
//
#include <hip/hip_runtime.h>
#include <math.h>

#define B_ 32
#define L_ 512
#define D_ 512
#define S_ 8

using f16x8 = __attribute__((ext_vector_type(8))) _Float16;
using f32x4 = __attribute__((ext_vector_type(4))) float;

__device__ __forceinline__ float sigm(float x) { return 1.0f / (1.0f + __expf(-x)); }

__device__ __forceinline__ void stage16(const _Float16* g, _Float16* l) {
    __builtin_amdgcn_global_load_lds(
        (const __attribute__((address_space(1))) void*)g,
        (__attribute__((address_space(3))) void*)l, 16, 0, 0);
}

// ---------------------------------------------------------------------------
// fp32 rows -> tiled fp16 [rtile][kt16][kq4][row128][8]
// ---------------------------------------------------------------------------
__global__ __launch_bounds__(256) void conv_tiled_kernel(
    const float* __restrict__ in, _Float16* __restrict__ outh)
{
    __shared__ __align__(16) float scr[4096];     // [kq4][row128][8]
    const int t = threadIdx.x;
    const size_t base_in  = (size_t)blockIdx.x * 128 * D_;
    const size_t base_out = (size_t)blockIdx.x * 65536;
    for (int kt = 0; kt < 16; ++kt) {
        if (kt) __syncthreads();
        #pragma unroll
        for (int f = 0; f < 4; ++f) {
            const int fi = t + f * 256;            // 0..1023
            const int row = fi >> 3, c4 = fi & 7;
            float4 v = *(const float4*)(in + base_in + (size_t)row * D_ + kt * 32 + c4 * 4);
            *(float4*)(scr + ((c4 >> 1) * 128 + row) * 8 + (c4 & 1) * 4) = v;
        }
        __syncthreads();
        #pragma unroll
        for (int c = 0; c < 2; ++c) {
            const int s = t + c * 256;             // 0..511
            const float4 v0 = *(const float4*)(scr + s * 8);
            const float4 v1 = *(const float4*)(scr + s * 8 + 4);
            const float vv[8] = {v0.x, v0.y, v0.z, v0.w, v1.x, v1.y, v1.z, v1.w};
            f16x8 h;
            #pragma unroll
            for (int i = 0; i < 8; ++i) h[i] = (_Float16)vv[i];
            *(f16x8*)(outh + base_out + kt * 4096 + s * 8) = h;
        }
    }
}

// ---------------------------------------------------------------------------
// Mr [k][d][e] fp32 -> fp16 tiled over n=k*512+e: [ntile][kt_d][kq][n128][8d]
// ---------------------------------------------------------------------------
__global__ __launch_bounds__(256) void conv_mrT_kernel(
    const float* __restrict__ Mr, _Float16* __restrict__ out)
{
    __shared__ float tile[32][33];
    const int k = blockIdx.z;
    const int e0 = blockIdx.x * 32, d0 = blockIdx.y * 32;
    const int tx = threadIdx.x & 31, ty = threadIdx.x >> 5;
    #pragma unroll
    for (int i = 0; i < 4; ++i) {
        const int dl = ty + i * 8;
        tile[dl][tx] = Mr[(size_t)k * (D_ * D_) + (size_t)(d0 + dl) * D_ + e0 + tx];
    }
    __syncthreads();
    if (threadIdx.x < 128) {
        const int el = threadIdx.x & 31, dc = threadIdx.x >> 5;   // dc 0..3
        f16x8 h;
        #pragma unroll
        for (int i = 0; i < 8; ++i) h[i] = (_Float16)tile[dc * 8 + i][el];
        const int e = e0 + el, d = d0 + dc * 8;
        const size_t addr = (size_t)(k * 4 + (e >> 7)) * 65536
                          + (size_t)(d >> 5) * 4096 + ((d >> 3) & 3) * 1024
                          + (size_t)(e & 127) * 8;
        *(f16x8*)(out + addr) = h;
    }
}

// ---------------------------------------------------------------------------
// Projections (fp32, tiny)
// ---------------------------------------------------------------------------
__global__ __launch_bounds__(256) void proj_kernel(
    const float* __restrict__ a1, const float* __restrict__ a2,
    const float* __restrict__ Wg, const float* __restrict__ V,
    const float* __restrict__ Bg,
    float* __restrict__ G1, float* __restrict__ G2,
    float* __restrict__ S1, float* __restrict__ S2)
{
    const int wave = threadIdx.x >> 6;
    const int lane = threadIdx.x & 63;
    const int r = blockIdx.x * 4 + wave;
    const float* a1r = a1 + (size_t)r * D_;
    const float* a2r = a2 + (size_t)r * D_;
    float g1[S_] = {}, g2[S_] = {}, s1[S_] = {}, s2[S_] = {};
    for (int d = lane; d < D_; d += 64) {
        float x1 = a1r[d], x2 = a2r[d];
        const float* wga = Wg + d * S_;
        const float* wgb = Wg + (D_ + d) * S_;
        const float* va  = V  + d * S_;
        const float* vb  = V  + (D_ + d) * S_;
        #pragma unroll
        for (int s = 0; s < S_; ++s) {
            g1[s] += x1 * wga[s];
            g2[s] += x2 * wgb[s];
            s1[s] += x1 * va[s];
            s2[s] += x2 * vb[s];
        }
    }
    #pragma unroll
    for (int off = 32; off > 0; off >>= 1) {
        #pragma unroll
        for (int s = 0; s < S_; ++s) {
            g1[s] += __shfl_down(g1[s], off);
            g2[s] += __shfl_down(g2[s], off);
            s1[s] += __shfl_down(s1[s], off);
            s2[s] += __shfl_down(s2[s], off);
        }
    }
    if (lane == 0) {
        #pragma unroll
        for (int s = 0; s < S_; ++s) {
            G1[(size_t)r * S_ + s] = g1[s] + Bg[s];
            G2[(size_t)r * S_ + s] = g2[s];
            S1[(size_t)r * S_ + s] = s1[s];
            S2[(size_t)r * S_ + s] = s2[s];
        }
    }
}

// ---------------------------------------------------------------------------
// GEMM A: A1 = a1 @ Mr (single fp16). Double-buffered LDS (64 KB), BK=64.
// Swizzled grid: same-y siblings (all 32 ntiles) share an XCD.
// Output A1 fp16, tiled [itile][kt_e][kq_e][m=k*16+i15][8e], chunk-local.
// ---------------------------------------------------------------------------
__global__ __launch_bounds__(256) void gemm_a_kernel(
    const _Float16* __restrict__ Ah, const _Float16* __restrict__ Bt,
    _Float16* __restrict__ C, int ytile0, int nY)
{
    __shared__ __align__(16) _Float16 lds[32768];   // 64 KB: 2 x (As 16KB + Bs 16KB)

    const int t = threadIdx.x;
    const int lane = t & 63, wv = t >> 6;
    const int wm = wv >> 1, wn = wv & 1;
    const int q = lane >> 4, i15 = lane & 15;

    int nt, yl;
    {
        const int id = blockIdx.x;
        if (nY >= 8) { const int y0 = id & 7; const int r = id >> 3; nt = r & 31; yl = (r >> 5) * 8 + y0; }
        else         { nt = id & 31; yl = id >> 5; }
    }
    const size_t abase = (size_t)(ytile0 + yl) * 65536;
    const size_t bbase = (size_t)nt * 65536;
    const int kblk = nt >> 2;
    const int e0 = (nt & 3) * 128;
    const int r0 = yl * 128;

    f32x4 acc[4][4];
    const f32x4 zero = {0.f, 0.f, 0.f, 0.f};
    #pragma unroll
    for (int a = 0; a < 4; ++a)
        #pragma unroll
        for (int b = 0; b < 4; ++b) acc[a][b] = zero;

    auto stage_it = [&](int kt2, int buf) {
        _Float16* As = lds + buf * 16384;
        _Float16* Bs = As + 8192;
        const size_t ab = abase + kt2 * 8192;
        const size_t bb = bbase + kt2 * 8192;
        #pragma unroll
        for (int c = 0; c < 4; ++c) {
            const int s8 = t + c * 256;
            stage16(Ah + ab + s8 * 8, As + s8 * 8);
            stage16(Bt + bb + s8 * 8, Bs + s8 * 8);
        }
    };

    stage_it(0, 0);
    __syncthreads();
    for (int kt2 = 0; kt2 < 8; ++kt2) {
        const int cur = kt2 & 1;
        if (kt2 < 7) stage_it(kt2 + 1, cur ^ 1);
        const _Float16* As = lds + cur * 16384;
        const _Float16* Bs = As + 8192;
        #pragma unroll
        for (int kk2 = 0; kk2 < 2; ++kk2) {
            const int kq = kk2 * 4 + q;
            f16x8 bfr[4];
            #pragma unroll
            for (int nn = 0; nn < 4; ++nn)
                bfr[nn] = *(const f16x8*)(Bs + ((size_t)kq * 128 + wn * 64 + nn * 16 + i15) * 8);
            #pragma unroll
            for (int mt = 0; mt < 4; ++mt) {
                const int m = wm * 64 + mt * 16 + i15;
                f16x8 a = *(const f16x8*)(As + ((size_t)kq * 128 + m) * 8);
                #pragma unroll
                for (int nn = 0; nn < 4; ++nn)
                    acc[mt][nn] = __builtin_amdgcn_mfma_f32_16x16x32_f16(a, bfr[nn], acc[mt][nn], 0, 0, 0);
            }
        }
        __syncthreads();
    }

    // epilogue: per-wave LDS transpose -> tiled fp16 A1, 256B-contiguous stores
    float* scr = (float*)lds + wv * 1104;           // 16 x 68 floats
    #pragma unroll
    for (int mt = 0; mt < 4; ++mt) {
        #pragma unroll
        for (int nn = 0; nn < 4; ++nn)
            #pragma unroll
            for (int r = 0; r < 4; ++r)
                scr[(q * 4 + r) * 68 + nn * 16 + i15] = acc[mt][nn][r];
        __builtin_amdgcn_s_waitcnt(0);
        #pragma unroll
        for (int cc = 0; cc < 2; ++cc) {
            const int row = lane & 15;
            const int ech = (lane >> 4) + cc * 4;   // 0..7
            const float4 v0 = *(const float4*)(scr + row * 68 + ech * 8);
            const float4 v1 = *(const float4*)(scr + row * 68 + ech * 8 + 4);
            const float vv[8] = {v0.x, v0.y, v0.z, v0.w, v1.x, v1.y, v1.z, v1.w};
            f16x8 h;
            #pragma unroll
            for (int i = 0; i < 8; ++i) h[i] = (_Float16)vv[i];
            const int e = e0 + wn * 64 + ech * 8;
            const int ig = r0 + wm * 64 + mt * 16 + row;
            const size_t addr = (size_t)(ig >> 4) * 65536
                              + (size_t)(e >> 5) * 4096 + ((e >> 3) & 3) * 1024
                              + (size_t)(kblk * 16 + row) * 8;
            *(f16x8*)(C + addr) = h;
        }
        __builtin_amdgcn_s_waitcnt(0);
    }
}

// ---------------------------------------------------------------------------
// GEMM B + fused epilogue. Double-buffered LDS (64 KB), BK=64.
// Swizzled grid: all blocks of one batch share an XCD (a2/A1 L2-resident).
// ---------------------------------------------------------------------------
__global__ __launch_bounds__(256) void gemm_b_kernel(
    const _Float16* __restrict__ A1, const _Float16* __restrict__ a2t,
    const float* __restrict__ G1, const float* __restrict__ G2,
    const float* __restrict__ S1, const float* __restrict__ S2,
    const float* __restrict__ U, const float* __restrict__ bvec,
    float* __restrict__ out, int b0, int NB)
{
    __shared__ __align__(16) _Float16 lds[32768];   // 64 KB: 2 x (As + Bs)

    const int t = threadIdx.x;
    const int lane = t & 63, wv = t >> 6;
    const int wm = wv >> 1, wn = wv & 1;
    const int q = lane >> 4, i15 = lane & 15;

    int bl, jt, y;
    {
        const int id = blockIdx.x;
        bl = id & (NB - 1);
        const int r = id / NB;
        jt = r & 3;
        y = r >> 2;
    }
    const int bg = b0 + bl;
    const int j0 = jt * 128;
    const size_t abase = (size_t)(bl * 32 + y) * 65536;
    const size_t bbase = (size_t)(bg * 4 + jt) * 65536;

    f32x4 acc[4][4];
    const f32x4 zero = {0.f, 0.f, 0.f, 0.f};
    #pragma unroll
    for (int a = 0; a < 4; ++a)
        #pragma unroll
        for (int b = 0; b < 4; ++b) acc[a][b] = zero;

    auto stage_it = [&](int kt2, int buf) {
        _Float16* As = lds + buf * 16384;
        _Float16* Bs = As + 8192;
        const size_t ab = abase + kt2 * 8192;
        const size_t bb = bbase + kt2 * 8192;
        #pragma unroll
        for (int c = 0; c < 4; ++c) {
            const int s8 = t + c * 256;
            stage16(A1 + ab + s8 * 8, As + s8 * 8);
            stage16(a2t + bb + s8 * 8, Bs + s8 * 8);
        }
    };

    stage_it(0, 0);
    __syncthreads();
    for (int kt2 = 0; kt2 < 8; ++kt2) {
        const int cur = kt2 & 1;
        if (kt2 < 7) stage_it(kt2 + 1, cur ^ 1);
        const _Float16* As = lds + cur * 16384;
        const _Float16* Bs = As + 8192;
        #pragma unroll
        for (int kk2 = 0; kk2 < 2; ++kk2) {
            const int kq = kk2 * 4 + q;
            f16x8 bfr[4];
            #pragma unroll
            for (int nn = 0; nn < 4; ++nn)
                bfr[nn] = *(const f16x8*)(Bs + ((size_t)kq * 128 + wn * 64 + nn * 16 + i15) * 8);
            #pragma unroll
            for (int mt = 0; mt < 4; ++mt) {
                const int m = wm * 64 + mt * 16 + i15;
                f16x8 a = *(const f16x8*)(As + ((size_t)kq * 128 + m) * 8);
                #pragma unroll
                for (int nn = 0; nn < 4; ++nn)
                    acc[mt][nn] = __builtin_amdgcn_mfma_f32_16x16x32_f16(a, bfr[nn], acc[mt][nn], 0, 0, 0);
            }
        }
        __syncthreads();
    }

    // epilogue: thread covers i = y*16 + q*4 + r (4 i), j (4 nt), k = wm*4+mt
    float U4[4];
    float cbias = 0.f;
    #pragma unroll
    for (int k = 0; k < 8; ++k) cbias += U[k] * bvec[k];
    #pragma unroll
    for (int mt = 0; mt < 4; ++mt) U4[mt] = U[wm * 4 + mt];

    float g1v[4][4], s1v[4][4];
    #pragma unroll
    for (int r = 0; r < 4; ++r) {
        const int ig = y * 16 + q * 4 + r;
        const float4 g1 = *(const float4*)(G1 + ((size_t)bg * L_ + ig) * S_ + wm * 4);
        const float4 s1 = *(const float4*)(S1 + ((size_t)bg * L_ + ig) * S_ + wm * 4);
        g1v[r][0] = g1.x; g1v[r][1] = g1.y; g1v[r][2] = g1.z; g1v[r][3] = g1.w;
        s1v[r][0] = s1.x; s1v[r][1] = s1.y; s1v[r][2] = s1.z; s1v[r][3] = s1.w;
    }

    float part[4][4];   // [nn][r]
    #pragma unroll
    for (int nn = 0; nn < 4; ++nn) {
        const int j = j0 + wn * 64 + nn * 16 + i15;
        const float4 g2 = *(const float4*)(G2 + ((size_t)bg * L_ + j) * S_ + wm * 4);
        const float4 s2 = *(const float4*)(S2 + ((size_t)bg * L_ + j) * S_ + wm * 4);
        const float g2p[4] = {g2.x, g2.y, g2.z, g2.w};
        const float s2p[4] = {s2.x, s2.y, s2.z, s2.w};
        #pragma unroll
        for (int r = 0; r < 4; ++r) {
            float p = 0.f;
            #pragma unroll
            for (int mt = 0; mt < 4; ++mt) {
                const float g  = sigm(g1v[r][mt] + g2p[mt]);
                const float si = sigm(s1v[r][mt] + s2p[mt]);
                p += U4[mt] * (acc[mt][nn][r] * g + si * (1.f - g));
            }
            part[nn][r] = p;
        }
    }

    // cross-wave k-half exchange (wm=0 <-> wm=1 partner = t +/- 128)
    float* xb = (float*)lds;                        // 16 KB
    #pragma unroll
    for (int nn = 0; nn < 4; ++nn)
        *(float4*)(xb + t * 16 + nn * 4) = *(const float4*)&part[nn][0];
    __syncthreads();
    if (wm == 0) {
        #pragma unroll
        for (int nn = 0; nn < 4; ++nn) {
            const int j = j0 + wn * 64 + nn * 16 + i15;
            const float4 o = *(const float4*)(xb + (t + 128) * 16 + nn * 4);
            const float op[4] = {o.x, o.y, o.z, o.w};
            #pragma unroll
            for (int r = 0; r < 4; ++r) {
                const int ig = y * 16 + q * 4 + r;
                out[((size_t)bg * L_ + ig) * L_ + j] = sigm(part[nn][r] + op[r] + cbias);
            }
        }
    }
}

// ---------------------------------------------------------------------------
extern "C" void kernel_launch(void* const* d_in, const int* in_sizes, int n_in,
                              void* d_out, int out_size, void* d_ws, size_t ws_size,
                              hipStream_t stream)
{
    const float* arg1 = (const float*)d_in[0];
    const float* arg2 = (const float*)d_in[1];
    const float* Wg   = (const float*)d_in[2];
    const float* Bg   = (const float*)d_in[3];
    const float* Mr   = (const float*)d_in[4];
    const float* V    = (const float*)d_in[5];
    const float* bvec = (const float*)d_in[6];
    const float* U    = (const float*)d_in[7];
    float* out = (float*)d_out;

    char* w = (char*)d_ws;
    size_t off = 0;
    auto nxt = [&](size_t bytes) -> void* {
        void* p = w + off;
        off = (off + bytes + 255) & ~(size_t)255;
        return p;
    };

    _Float16* mrT = (_Float16*)nxt((size_t)S_ * D_ * D_ * 2);
    float* G1 = (float*)nxt((size_t)B_ * L_ * S_ * 4);
    float* G2 = (float*)nxt((size_t)B_ * L_ * S_ * 4);
    float* S1 = (float*)nxt((size_t)B_ * L_ * S_ * 4);
    float* S2 = (float*)nxt((size_t)B_ * L_ * S_ * 4);
    _Float16* a1h = (_Float16*)nxt((size_t)B_ * L_ * D_ * 2);
    _Float16* a2h = (_Float16*)nxt((size_t)B_ * L_ * D_ * 2);
    const size_t fixed = off;

    const size_t perA1 = (size_t)L_ * S_ * D_ * 2;   // 4.19 MB per batch
    int NB = 8;
    while (NB > 1 && fixed + (size_t)NB * perA1 + 4096 > ws_size) NB >>= 1;
    _Float16* A1 = (_Float16*)nxt((size_t)NB * perA1);

    conv_mrT_kernel<<<dim3(16, 16, 8), 256, 0, stream>>>(Mr, mrT);
    proj_kernel<<<dim3(B_ * L_ / 4), 256, 0, stream>>>(arg1, arg2, Wg, V, Bg, G1, G2, S1, S2);
    conv_tiled_kernel<<<dim3(B_ * L_ / 128), 256, 0, stream>>>(arg1, a1h);
    conv_tiled_kernel<<<dim3(B_ * L_ / 128), 256, 0, stream>>>(arg2, a2h);

    for (int b0 = 0; b0 < B_; b0 += NB) {
        gemm_a_kernel<<<dim3(32 * NB * 4), 256, 0, stream>>>(a1h, mrT, A1, b0 * 4, NB * 4);
        gemm_b_kernel<<<dim3(NB * 128), 256, 0, stream>>>(
            A1, a2h, G1, G2, S1, S2, U, bvec, out, b0, NB);
    }
}

// Round 5
// 435.427 us; speedup vs baseline: 3.9729x; 1.1427x over previous
//
#include <hip/hip_runtime.h>
#include <math.h>

#define B_ 32
#define L_ 512
#define D_ 512
#define S_ 8

using f16x8 = __attribute__((ext_vector_type(8))) _Float16;
using f32x4 = __attribute__((ext_vector_type(4))) float;

__device__ __forceinline__ float sigm(float x) { return 1.0f / (1.0f + __expf(-x)); }

__device__ __forceinline__ void stage16(const _Float16* g, _Float16* l) {
    __builtin_amdgcn_global_load_lds(
        (const __attribute__((address_space(1))) void*)g,
        (__attribute__((address_space(3))) void*)l, 16, 0, 0);
}

// ---------------------------------------------------------------------------
// fp32 rows -> tiled fp16 [rtile][kt16][kq4][row128][8].  Block = (rtile, kt-quarter).
// ---------------------------------------------------------------------------
__global__ __launch_bounds__(256) void conv_tiled_kernel(
    const float* __restrict__ in, _Float16* __restrict__ outh)
{
    __shared__ __align__(16) float scr[4096];     // [kq4][row128][8]
    const int t = threadIdx.x;
    const int rt = blockIdx.x & 127;
    const int kt0 = (blockIdx.x >> 7) * 4;
    const size_t base_in  = (size_t)rt * 128 * D_;
    const size_t base_out = (size_t)rt * 65536;
    for (int kt = kt0; kt < kt0 + 4; ++kt) {
        if (kt != kt0) __syncthreads();
        #pragma unroll
        for (int f = 0; f < 4; ++f) {
            const int fi = t + f * 256;            // 0..1023
            const int row = fi >> 3, c4 = fi & 7;
            float4 v = *(const float4*)(in + base_in + (size_t)row * D_ + kt * 32 + c4 * 4);
            *(float4*)(scr + ((c4 >> 1) * 128 + row) * 8 + (c4 & 1) * 4) = v;
        }
        __syncthreads();
        #pragma unroll
        for (int c = 0; c < 2; ++c) {
            const int s = t + c * 256;             // 0..511
            const float4 v0 = *(const float4*)(scr + s * 8);
            const float4 v1 = *(const float4*)(scr + s * 8 + 4);
            const float vv[8] = {v0.x, v0.y, v0.z, v0.w, v1.x, v1.y, v1.z, v1.w};
            f16x8 h;
            #pragma unroll
            for (int i = 0; i < 8; ++i) h[i] = (_Float16)vv[i];
            *(f16x8*)(outh + base_out + kt * 4096 + s * 8) = h;
        }
    }
}

// ---------------------------------------------------------------------------
// Mr [k][d][e] fp32 -> fp16 tiled over n=k*512+e: [ntile][kt_d][kq][n128][8d]
// ---------------------------------------------------------------------------
__global__ __launch_bounds__(256) void conv_mrT_kernel(
    const float* __restrict__ Mr, _Float16* __restrict__ out)
{
    __shared__ float tile[32][33];
    const int k = blockIdx.z;
    const int e0 = blockIdx.x * 32, d0 = blockIdx.y * 32;
    const int tx = threadIdx.x & 31, ty = threadIdx.x >> 5;
    #pragma unroll
    for (int i = 0; i < 4; ++i) {
        const int dl = ty + i * 8;
        tile[dl][tx] = Mr[(size_t)k * (D_ * D_) + (size_t)(d0 + dl) * D_ + e0 + tx];
    }
    __syncthreads();
    if (threadIdx.x < 128) {
        const int el = threadIdx.x & 31, dc = threadIdx.x >> 5;   // dc 0..3
        f16x8 h;
        #pragma unroll
        for (int i = 0; i < 8; ++i) h[i] = (_Float16)tile[dc * 8 + i][el];
        const int e = e0 + el, d = d0 + dc * 8;
        const size_t addr = (size_t)(k * 4 + (e >> 7)) * 65536
                          + (size_t)(d >> 5) * 4096 + ((d >> 3) & 3) * 1024
                          + (size_t)(e & 127) * 8;
        *(f16x8*)(out + addr) = h;
    }
}

// ---------------------------------------------------------------------------
// Pack Wg/V -> Wt[side][kt][q][n16][j8] fp16, element = W'side[d=kt*32+q*8+j][n]
// W'0[d][n] = n<8 ? Wg[d][n] : V[d][n-8];  W'1 uses d+512.
// ---------------------------------------------------------------------------
__global__ __launch_bounds__(256) void convW_kernel(
    const float* __restrict__ Wg, const float* __restrict__ V,
    _Float16* __restrict__ Wt)
{
    const int idx = blockIdx.x * 256 + threadIdx.x;    // 0..16383
    const int j = idx & 7;
    const int n = (idx >> 3) & 15;
    const int q = (idx >> 7) & 3;
    const int kt = (idx >> 9) & 15;
    const int side = idx >> 13;
    const int d = side * 512 + kt * 32 + q * 8 + j;
    const float v = (n < 8) ? Wg[d * S_ + n] : V[d * S_ + (n - 8)];
    Wt[idx] = (_Float16)v;
}

// ---------------------------------------------------------------------------
// MFMA projections: side0: [G1|S1] = a1 @ W'0 (+Bg on G1); side1: [G2|S2].
// One wave = 16 rows x 16 outs, K=512 via 16 MFMAs. Reads tiled fp16 acts.
// ---------------------------------------------------------------------------
__global__ __launch_bounds__(256) void proj_mfma_kernel(
    const _Float16* __restrict__ a1h, const _Float16* __restrict__ a2h,
    const _Float16* __restrict__ Wt, const float* __restrict__ Bg,
    float* __restrict__ G1, float* __restrict__ G2,
    float* __restrict__ S1, float* __restrict__ S2)
{
    const int t = threadIdx.x;
    const int lane = t & 63, wv = t >> 6;
    const int q = lane >> 4, i15 = lane & 15;
    const int id = blockIdx.x;
    const int side = id >> 8;                  // 0..1
    const int rb = id & 255;                   // 64-row group
    const int rtile = rb >> 1;
    const int rbase = (rb & 1) * 64 + wv * 16; // row base within rtile

    const _Float16* A = (side ? a2h : a1h) + (size_t)rtile * 65536;
    const _Float16* W = Wt + side * 8192;

    f32x4 acc = {0.f, 0.f, 0.f, 0.f};
    #pragma unroll
    for (int kt = 0; kt < 16; ++kt) {
        f16x8 a = *(const f16x8*)(A + (size_t)kt * 4096 + q * 1024 + (rbase + i15) * 8);
        f16x8 b = *(const f16x8*)(W + (size_t)(kt * 4 + q) * 128 + i15 * 8);
        acc = __builtin_amdgcn_mfma_f32_16x16x32_f16(a, b, acc, 0, 0, 0);
    }

    float* dst = (i15 < 8) ? (side ? G2 : G1) : (side ? S2 : S1);
    const int n = i15 & 7;
    const float add = (side == 0 && i15 < 8) ? Bg[n] : 0.f;
    const int R0 = rtile * 128 + rbase + q * 4;
    #pragma unroll
    for (int r = 0; r < 4; ++r)
        dst[(size_t)(R0 + r) * S_ + n] = acc[r] + add;
}

// ---------------------------------------------------------------------------
// GEMM A: A1 = a1 @ Mr (single fp16). Double-buffered LDS (64 KB), BK=64.
// Swizzled grid: same-y siblings (all 32 ntiles) share an XCD.
// Output A1 fp16, tiled [itile][kt_e][kq_e][m=k*16+i15][8e], chunk-local.
// ---------------------------------------------------------------------------
__global__ __launch_bounds__(256) void gemm_a_kernel(
    const _Float16* __restrict__ Ah, const _Float16* __restrict__ Bt,
    _Float16* __restrict__ C, int ytile0, int nY)
{
    __shared__ __align__(16) _Float16 lds[32768];   // 64 KB: 2 x (As 16KB + Bs 16KB)

    const int t = threadIdx.x;
    const int lane = t & 63, wv = t >> 6;
    const int wm = wv >> 1, wn = wv & 1;
    const int q = lane >> 4, i15 = lane & 15;

    int nt, yl;
    {
        const int id = blockIdx.x;
        if (nY >= 8) { const int y0 = id & 7; const int r = id >> 3; nt = r & 31; yl = (r >> 5) * 8 + y0; }
        else         { nt = id & 31; yl = id >> 5; }
    }
    const size_t abase = (size_t)(ytile0 + yl) * 65536;
    const size_t bbase = (size_t)nt * 65536;
    const int kblk = nt >> 2;
    const int e0 = (nt & 3) * 128;
    const int r0 = yl * 128;

    f32x4 acc[4][4];
    const f32x4 zero = {0.f, 0.f, 0.f, 0.f};
    #pragma unroll
    for (int a = 0; a < 4; ++a)
        #pragma unroll
        for (int b = 0; b < 4; ++b) acc[a][b] = zero;

    auto stage_it = [&](int kt2, int buf) {
        _Float16* As = lds + buf * 16384;
        _Float16* Bs = As + 8192;
        const size_t ab = abase + kt2 * 8192;
        const size_t bb = bbase + kt2 * 8192;
        #pragma unroll
        for (int c = 0; c < 4; ++c) {
            const int s8 = t + c * 256;
            stage16(Ah + ab + s8 * 8, As + s8 * 8);
            stage16(Bt + bb + s8 * 8, Bs + s8 * 8);
        }
    };

    stage_it(0, 0);
    __syncthreads();
    for (int kt2 = 0; kt2 < 8; ++kt2) {
        const int cur = kt2 & 1;
        if (kt2 < 7) stage_it(kt2 + 1, cur ^ 1);
        const _Float16* As = lds + cur * 16384;
        const _Float16* Bs = As + 8192;
        #pragma unroll
        for (int kk2 = 0; kk2 < 2; ++kk2) {
            const int kq = kk2 * 4 + q;
            f16x8 bfr[4];
            #pragma unroll
            for (int nn = 0; nn < 4; ++nn)
                bfr[nn] = *(const f16x8*)(Bs + ((size_t)kq * 128 + wn * 64 + nn * 16 + i15) * 8);
            #pragma unroll
            for (int mt = 0; mt < 4; ++mt) {
                const int m = wm * 64 + mt * 16 + i15;
                f16x8 a = *(const f16x8*)(As + ((size_t)kq * 128 + m) * 8);
                #pragma unroll
                for (int nn = 0; nn < 4; ++nn)
                    acc[mt][nn] = __builtin_amdgcn_mfma_f32_16x16x32_f16(a, bfr[nn], acc[mt][nn], 0, 0, 0);
            }
        }
        __syncthreads();
    }

    // epilogue: per-wave LDS transpose -> tiled fp16 A1, 256B-contiguous stores
    float* scr = (float*)lds + wv * 1104;           // 16 x 68 floats
    #pragma unroll
    for (int mt = 0; mt < 4; ++mt) {
        #pragma unroll
        for (int nn = 0; nn < 4; ++nn)
            #pragma unroll
            for (int r = 0; r < 4; ++r)
                scr[(q * 4 + r) * 68 + nn * 16 + i15] = acc[mt][nn][r];
        __builtin_amdgcn_s_waitcnt(0);
        #pragma unroll
        for (int cc = 0; cc < 2; ++cc) {
            const int row = lane & 15;
            const int ech = (lane >> 4) + cc * 4;   // 0..7
            const float4 v0 = *(const float4*)(scr + row * 68 + ech * 8);
            const float4 v1 = *(const float4*)(scr + row * 68 + ech * 8 + 4);
            const float vv[8] = {v0.x, v0.y, v0.z, v0.w, v1.x, v1.y, v1.z, v1.w};
            f16x8 h;
            #pragma unroll
            for (int i = 0; i < 8; ++i) h[i] = (_Float16)vv[i];
            const int e = e0 + wn * 64 + ech * 8;
            const int ig = r0 + wm * 64 + mt * 16 + row;
            const size_t addr = (size_t)(ig >> 4) * 65536
                              + (size_t)(e >> 5) * 4096 + ((e >> 3) & 3) * 1024
                              + (size_t)(kblk * 16 + row) * 8;
            *(f16x8*)(C + addr) = h;
        }
        __builtin_amdgcn_s_waitcnt(0);
    }
}

// ---------------------------------------------------------------------------
// GEMM B + fused epilogue. Double-buffered LDS (64 KB), BK=64.
// Swizzled grid: all blocks of one batch share an XCD (a2/A1 L2-resident).
// ---------------------------------------------------------------------------
__global__ __launch_bounds__(256) void gemm_b_kernel(
    const _Float16* __restrict__ A1, const _Float16* __restrict__ a2t,
    const float* __restrict__ G1, const float* __restrict__ G2,
    const float* __restrict__ S1, const float* __restrict__ S2,
    const float* __restrict__ U, const float* __restrict__ bvec,
    float* __restrict__ out, int b0, int NB)
{
    __shared__ __align__(16) _Float16 lds[32768];   // 64 KB: 2 x (As + Bs)

    const int t = threadIdx.x;
    const int lane = t & 63, wv = t >> 6;
    const int wm = wv >> 1, wn = wv & 1;
    const int q = lane >> 4, i15 = lane & 15;

    int bl, jt, y;
    {
        const int id = blockIdx.x;
        bl = id & (NB - 1);
        const int r = id / NB;
        jt = r & 3;
        y = r >> 2;
    }
    const int bg = b0 + bl;
    const int j0 = jt * 128;
    const size_t abase = (size_t)(bl * 32 + y) * 65536;
    const size_t bbase = (size_t)(bg * 4 + jt) * 65536;

    f32x4 acc[4][4];
    const f32x4 zero = {0.f, 0.f, 0.f, 0.f};
    #pragma unroll
    for (int a = 0; a < 4; ++a)
        #pragma unroll
        for (int b = 0; b < 4; ++b) acc[a][b] = zero;

    auto stage_it = [&](int kt2, int buf) {
        _Float16* As = lds + buf * 16384;
        _Float16* Bs = As + 8192;
        const size_t ab = abase + kt2 * 8192;
        const size_t bb = bbase + kt2 * 8192;
        #pragma unroll
        for (int c = 0; c < 4; ++c) {
            const int s8 = t + c * 256;
            stage16(A1 + ab + s8 * 8, As + s8 * 8);
            stage16(a2t + bb + s8 * 8, Bs + s8 * 8);
        }
    };

    stage_it(0, 0);
    __syncthreads();
    for (int kt2 = 0; kt2 < 8; ++kt2) {
        const int cur = kt2 & 1;
        if (kt2 < 7) stage_it(kt2 + 1, cur ^ 1);
        const _Float16* As = lds + cur * 16384;
        const _Float16* Bs = As + 8192;
        #pragma unroll
        for (int kk2 = 0; kk2 < 2; ++kk2) {
            const int kq = kk2 * 4 + q;
            f16x8 bfr[4];
            #pragma unroll
            for (int nn = 0; nn < 4; ++nn)
                bfr[nn] = *(const f16x8*)(Bs + ((size_t)kq * 128 + wn * 64 + nn * 16 + i15) * 8);
            #pragma unroll
            for (int mt = 0; mt < 4; ++mt) {
                const int m = wm * 64 + mt * 16 + i15;
                f16x8 a = *(const f16x8*)(As + ((size_t)kq * 128 + m) * 8);
                #pragma unroll
                for (int nn = 0; nn < 4; ++nn)
                    acc[mt][nn] = __builtin_amdgcn_mfma_f32_16x16x32_f16(a, bfr[nn], acc[mt][nn], 0, 0, 0);
            }
        }
        __syncthreads();
    }

    // epilogue: thread covers i = y*16 + q*4 + r (4 i), j (4 nt), k = wm*4+mt
    float U4[4];
    float cbias = 0.f;
    #pragma unroll
    for (int k = 0; k < 8; ++k) cbias += U[k] * bvec[k];
    #pragma unroll
    for (int mt = 0; mt < 4; ++mt) U4[mt] = U[wm * 4 + mt];

    float g1v[4][4], s1v[4][4];
    #pragma unroll
    for (int r = 0; r < 4; ++r) {
        const int ig = y * 16 + q * 4 + r;
        const float4 g1 = *(const float4*)(G1 + ((size_t)bg * L_ + ig) * S_ + wm * 4);
        const float4 s1 = *(const float4*)(S1 + ((size_t)bg * L_ + ig) * S_ + wm * 4);
        g1v[r][0] = g1.x; g1v[r][1] = g1.y; g1v[r][2] = g1.z; g1v[r][3] = g1.w;
        s1v[r][0] = s1.x; s1v[r][1] = s1.y; s1v[r][2] = s1.z; s1v[r][3] = s1.w;
    }

    float part[4][4];   // [nn][r]
    #pragma unroll
    for (int nn = 0; nn < 4; ++nn) {
        const int j = j0 + wn * 64 + nn * 16 + i15;
        const float4 g2 = *(const float4*)(G2 + ((size_t)bg * L_ + j) * S_ + wm * 4);
        const float4 s2 = *(const float4*)(S2 + ((size_t)bg * L_ + j) * S_ + wm * 4);
        const float g2p[4] = {g2.x, g2.y, g2.z, g2.w};
        const float s2p[4] = {s2.x, s2.y, s2.z, s2.w};
        #pragma unroll
        for (int r = 0; r < 4; ++r) {
            float p = 0.f;
            #pragma unroll
            for (int mt = 0; mt < 4; ++mt) {
                const float g  = sigm(g1v[r][mt] + g2p[mt]);
                const float si = sigm(s1v[r][mt] + s2p[mt]);
                p += U4[mt] * (acc[mt][nn][r] * g + si * (1.f - g));
            }
            part[nn][r] = p;
        }
    }

    // cross-wave k-half exchange (wm=0 <-> wm=1 partner = t +/- 128)
    float* xb = (float*)lds;                        // 16 KB
    #pragma unroll
    for (int nn = 0; nn < 4; ++nn)
        *(float4*)(xb + t * 16 + nn * 4) = *(const float4*)&part[nn][0];
    __syncthreads();
    if (wm == 0) {
        #pragma unroll
        for (int nn = 0; nn < 4; ++nn) {
            const int j = j0 + wn * 64 + nn * 16 + i15;
            const float4 o = *(const float4*)(xb + (t + 128) * 16 + nn * 4);
            const float op[4] = {o.x, o.y, o.z, o.w};
            #pragma unroll
            for (int r = 0; r < 4; ++r) {
                const int ig = y * 16 + q * 4 + r;
                out[((size_t)bg * L_ + ig) * L_ + j] = sigm(part[nn][r] + op[r] + cbias);
            }
        }
    }
}

// ---------------------------------------------------------------------------
extern "C" void kernel_launch(void* const* d_in, const int* in_sizes, int n_in,
                              void* d_out, int out_size, void* d_ws, size_t ws_size,
                              hipStream_t stream)
{
    const float* arg1 = (const float*)d_in[0];
    const float* arg2 = (const float*)d_in[1];
    const float* Wg   = (const float*)d_in[2];
    const float* Bg   = (const float*)d_in[3];
    const float* Mr   = (const float*)d_in[4];
    const float* V    = (const float*)d_in[5];
    const float* bvec = (const float*)d_in[6];
    const float* U    = (const float*)d_in[7];
    float* out = (float*)d_out;

    char* w = (char*)d_ws;
    size_t off = 0;
    auto nxt = [&](size_t bytes) -> void* {
        void* p = w + off;
        off = (off + bytes + 255) & ~(size_t)255;
        return p;
    };

    _Float16* mrT = (_Float16*)nxt((size_t)S_ * D_ * D_ * 2);
    _Float16* Wt  = (_Float16*)nxt((size_t)2 * 16 * 4 * 16 * 8 * 2);
    float* G1 = (float*)nxt((size_t)B_ * L_ * S_ * 4);
    float* G2 = (float*)nxt((size_t)B_ * L_ * S_ * 4);
    float* S1 = (float*)nxt((size_t)B_ * L_ * S_ * 4);
    float* S2 = (float*)nxt((size_t)B_ * L_ * S_ * 4);
    _Float16* a1h = (_Float16*)nxt((size_t)B_ * L_ * D_ * 2);
    _Float16* a2h = (_Float16*)nxt((size_t)B_ * L_ * D_ * 2);
    const size_t fixed = off;

    const size_t perA1 = (size_t)L_ * S_ * D_ * 2;   // 4.19 MB per batch
    int NB = 8;
    while (NB > 1 && fixed + (size_t)NB * perA1 + 4096 > ws_size) NB >>= 1;
    _Float16* A1 = (_Float16*)nxt((size_t)NB * perA1);

    conv_mrT_kernel<<<dim3(16, 16, 8), 256, 0, stream>>>(Mr, mrT);
    conv_tiled_kernel<<<dim3(512), 256, 0, stream>>>(arg1, a1h);
    conv_tiled_kernel<<<dim3(512), 256, 0, stream>>>(arg2, a2h);
    convW_kernel<<<dim3(64), 256, 0, stream>>>(Wg, V, Wt);
    proj_mfma_kernel<<<dim3(512), 256, 0, stream>>>(a1h, a2h, Wt, Bg, G1, G2, S1, S2);

    for (int b0 = 0; b0 < B_; b0 += NB) {
        gemm_a_kernel<<<dim3(32 * NB * 4), 256, 0, stream>>>(a1h, mrT, A1, b0 * 4, NB * 4);
        gemm_b_kernel<<<dim3(NB * 128), 256, 0, stream>>>(
            A1, a2h, G1, G2, S1, S2, U, bvec, out, b0, NB);
    }
}